// Round 1
// baseline (573.687 us; speedup 1.0000x reference)
//
#include <hip/hip_runtime.h>

// AFGCN: N=50000 nodes, E=600000 edges, D=128, L=4.
// Inputs: x[N,128] f32, edge_index[2,E] int, Wn[4,128,128] f32, Wr[4,128,128] f32,
//         b[4,128] f32, fcW[128,1] f32, fcb[1] f32. Output: [N] f32.

#define D 128

__global__ void k_zero_i32(int* __restrict__ p, int n) {
    int i = blockIdx.x * blockDim.x + threadIdx.x;
    if (i < n) p[i] = 0;
}

__global__ void k_hist(const int* __restrict__ dst, int* __restrict__ cnt, int e) {
    int i = blockIdx.x * blockDim.x + threadIdx.x;
    if (i < e) atomicAdd(&cnt[dst[i]], 1);
}

// single-block exclusive scan of cnt[0..n) -> ro[0..n], ro[n] = total
__global__ __launch_bounds__(1024) void k_scan(const int* __restrict__ cnt,
                                               int* __restrict__ ro, int n) {
    __shared__ int s[1024];
    int tid = threadIdx.x;
    int chunk = (n + 1023) >> 10;
    int start = tid * chunk;
    int end = min(start + chunk, n);
    int sum = 0;
    for (int i = start; i < end; ++i) sum += cnt[i];
    s[tid] = sum;
    __syncthreads();
    for (int off = 1; off < 1024; off <<= 1) {
        int add = (tid >= off) ? s[tid - off] : 0;
        __syncthreads();
        s[tid] += add;
        __syncthreads();
    }
    int run = (tid == 0) ? 0 : s[tid - 1];
    for (int i = start; i < end; ++i) { ro[i] = run; run += cnt[i]; }
    if (tid == 1023) ro[n] = s[1023];
}

__global__ void k_copy_i32(const int* __restrict__ a, int* __restrict__ b, int n) {
    int i = blockIdx.x * blockDim.x + threadIdx.x;
    if (i < n) b[i] = a[i];
}

__global__ void k_scatter(const int* __restrict__ src, const int* __restrict__ dst,
                          int* __restrict__ cur, int* __restrict__ ssrc, int e) {
    int i = blockIdx.x * blockDim.x + threadIdx.x;
    if (i < e) {
        int pos = atomicAdd(&cur[dst[i]], 1);
        ssrc[pos] = src[i];
    }
}

// one block (128 threads) per node: agg[i][t] = sum_{edges into i} h[src][t]
__global__ __launch_bounds__(128) void k_agg(const float* __restrict__ h,
                                             const int* __restrict__ ro,
                                             const int* __restrict__ ssrc,
                                             float* __restrict__ agg) {
    int i = blockIdx.x;
    int t = threadIdx.x;
    int s = ro[i], e = ro[i + 1];
    float acc = 0.f;
    #pragma unroll 4
    for (int j = s; j < e; ++j) {
        acc += h[(size_t)ssrc[j] * D + t];
    }
    agg[(size_t)i * D + t] = acc;
}

// h_out = relu(agg @ Wn + h_in @ Wr + b) + x0 ; tile 64 rows x 128 cols, 256 thr
__global__ __launch_bounds__(256) void k_layer(const float* __restrict__ hin,
                                               const float* __restrict__ agg,
                                               const float* __restrict__ Wn,
                                               const float* __restrict__ Wr,
                                               const float* __restrict__ bias,
                                               const float* __restrict__ x0,
                                               float* __restrict__ hout, int n) {
    __shared__ float sa[64][D];
    __shared__ float sh[64][D];
    int tid = threadIdx.x;
    int row0 = blockIdx.x * 64;

    // stage 64x128 agg + h tiles (float4)
    for (int i = tid; i < 64 * (D / 4); i += 256) {
        int r = i >> 5;              // 32 float4 per row
        int c4 = (i & 31) << 2;
        int gr = row0 + r;
        float4 va, vh;
        if (gr < n) {
            va = *(const float4*)&agg[(size_t)gr * D + c4];
            vh = *(const float4*)&hin[(size_t)gr * D + c4];
        } else {
            va = make_float4(0.f, 0.f, 0.f, 0.f);
            vh = va;
        }
        *(float4*)&sa[r][c4] = va;
        *(float4*)&sh[r][c4] = vh;
    }
    __syncthreads();

    int cx = (tid & 31) << 2;   // 4 consecutive cols
    int ry = (tid >> 5) << 3;   // 8 consecutive rows
    float acc[8][4] = {};

    #pragma unroll 4
    for (int k = 0; k < D; ++k) {
        float4 wn = *(const float4*)&Wn[k * D + cx];
        float4 wr = *(const float4*)&Wr[k * D + cx];
        #pragma unroll
        for (int r = 0; r < 8; ++r) {
            float a = sa[ry + r][k];
            float hv = sh[ry + r][k];
            acc[r][0] = fmaf(a, wn.x, fmaf(hv, wr.x, acc[r][0]));
            acc[r][1] = fmaf(a, wn.y, fmaf(hv, wr.y, acc[r][1]));
            acc[r][2] = fmaf(a, wn.z, fmaf(hv, wr.z, acc[r][2]));
            acc[r][3] = fmaf(a, wn.w, fmaf(hv, wr.w, acc[r][3]));
        }
    }

    float4 bb = *(const float4*)&bias[cx];
    #pragma unroll
    for (int r = 0; r < 8; ++r) {
        int gr = row0 + ry + r;
        if (gr >= n) break;
        float4 xr = *(const float4*)&x0[(size_t)gr * D + cx];
        float4 o;
        o.x = fmaxf(acc[r][0] + bb.x, 0.f) + xr.x;
        o.y = fmaxf(acc[r][1] + bb.y, 0.f) + xr.y;
        o.z = fmaxf(acc[r][2] + bb.z, 0.f) + xr.z;
        o.w = fmaxf(acc[r][3] + bb.w, 0.f) + xr.w;
        *(float4*)&hout[(size_t)gr * D + cx] = o;
    }
}

// out[i] = dot(h[i], fcW) + fcb ; one wave per row, 4 rows per block
__global__ __launch_bounds__(256) void k_fc(const float* __restrict__ h,
                                            const float* __restrict__ fcW,
                                            const float* __restrict__ fcb,
                                            float* __restrict__ out, int n) {
    int lane = threadIdx.x & 63;
    int row = blockIdx.x * 4 + (threadIdx.x >> 6);
    if (row >= n) return;
    const float* hr = h + (size_t)row * D;
    float p = hr[lane] * fcW[lane] + hr[64 + lane] * fcW[64 + lane];
    #pragma unroll
    for (int off = 32; off > 0; off >>= 1) p += __shfl_down(p, off, 64);
    if (lane == 0) out[row] = p + fcb[0];
}

extern "C" void kernel_launch(void* const* d_in, const int* in_sizes, int n_in,
                              void* d_out, int out_size, void* d_ws, size_t ws_size,
                              hipStream_t stream) {
    const float* x    = (const float*)d_in[0];
    const int*   ei   = (const int*)d_in[1];
    const float* Wn   = (const float*)d_in[2];
    const float* Wr   = (const float*)d_in[3];
    const float* bias = (const float*)d_in[4];
    const float* fcW  = (const float*)d_in[5];
    const float* fcb  = (const float*)d_in[6];
    float* out = (float*)d_out;

    const int n = in_sizes[0] / D;     // 50000
    const int e = in_sizes[1] / 2;     // 600000
    const int Lnum = 4;

    const int* src = ei;
    const int* dst = ei + e;

    // workspace layout
    char* ws = (char*)d_ws;
    float* h_a   = (float*)ws;                         ws += (size_t)n * D * 4;
    float* h_b   = (float*)ws;                         ws += (size_t)n * D * 4;
    float* agg   = (float*)ws;                         ws += (size_t)n * D * 4;
    int*   ro    = (int*)ws;                           ws += (size_t)(n + 1) * 4;
    int*   cur   = (int*)ws;                           ws += (size_t)n * 4;
    int*   ssrc  = (int*)ws;                           ws += (size_t)e * 4;
    (void)ws_size;

    // ---- CSR build (per call; deterministic up to atomic order inside a segment)
    k_zero_i32<<<(n + 255) / 256, 256, 0, stream>>>(cur, n);
    k_hist<<<(e + 255) / 256, 256, 0, stream>>>(dst, cur, e);
    k_scan<<<1, 1024, 0, stream>>>(cur, ro, n);
    k_copy_i32<<<(n + 255) / 256, 256, 0, stream>>>(ro, cur, n);
    k_scatter<<<(e + 255) / 256, 256, 0, stream>>>(src, dst, cur, ssrc, e);

    // ---- layers
    const float* hin = x;
    float* hout = h_a;
    int gemm_blocks = (n + 63) / 64;
    for (int l = 0; l < Lnum; ++l) {
        k_agg<<<n, 128, 0, stream>>>(hin, ro, ssrc, agg);
        k_layer<<<gemm_blocks, 256, 0, stream>>>(hin, agg,
                Wn + (size_t)l * D * D, Wr + (size_t)l * D * D,
                bias + (size_t)l * D, x, hout, n);
        hin = hout;
        hout = (hout == h_a) ? h_b : h_a;
    }

    // ---- final fc
    k_fc<<<(n + 3) / 4, 256, 0, stream>>>(hin, fcW, fcb, out, n);
}

// Round 2
// 502.190 us; speedup vs baseline: 1.1424x; 1.1424x over previous
//
#include <hip/hip_runtime.h>

// AFGCN: N=50000 nodes, E=600000 edges, D=128, L=4.
// Inputs: x[N,128] f32, edge_index[2,E] int, Wn[4,128,128] f32, Wr[4,128,128] f32,
//         b[4,128] f32, fcW[128,1] f32, fcb[1] f32. Output: [N] f32.

#define D 128

__global__ void k_zero_i32(int* __restrict__ p, int n) {
    int i = blockIdx.x * blockDim.x + threadIdx.x;
    if (i < n) p[i] = 0;
}

__global__ void k_hist(const int* __restrict__ dst, int* __restrict__ cnt, int e) {
    int i = blockIdx.x * blockDim.x + threadIdx.x;
    if (i < e) atomicAdd(&cnt[dst[i]], 1);
}

// phase A: per-block exclusive scan of 1024 elements (256 thr x 4), block sums out
__global__ __launch_bounds__(256) void k_scan_a(const int* __restrict__ cnt,
                                                int* __restrict__ ro,
                                                int* __restrict__ bsum, int n) {
    __shared__ int s[256];
    int tid = threadIdx.x;
    int base = blockIdx.x * 1024 + tid * 4;
    int c[4];
    #pragma unroll
    for (int k = 0; k < 4; ++k) c[k] = (base + k < n) ? cnt[base + k] : 0;
    int tsum = c[0] + c[1] + c[2] + c[3];
    s[tid] = tsum;
    __syncthreads();
    #pragma unroll
    for (int off = 1; off < 256; off <<= 1) {
        int add = (tid >= off) ? s[tid - off] : 0;
        __syncthreads();
        s[tid] += add;
        __syncthreads();
    }
    int run = (tid == 0) ? 0 : s[tid - 1];
    #pragma unroll
    for (int k = 0; k < 4; ++k) {
        if (base + k < n) ro[base + k] = run;
        run += c[k];
    }
    if (tid == 255) bsum[blockIdx.x] = s[255];
}

// phase B: one wave scans the <=64 block sums (exclusive, in place), writes total
__global__ __launch_bounds__(64) void k_scan_b(int* __restrict__ bsum,
                                               int* __restrict__ ro, int nb, int n) {
    int tid = threadIdx.x;
    int orig = (tid < nb) ? bsum[tid] : 0;
    int v = orig;
    #pragma unroll
    for (int off = 1; off < 64; off <<= 1) {
        int u = __shfl_up(v, off, 64);
        if (tid >= off) v += u;
    }
    if (tid < nb) bsum[tid] = v - orig;    // exclusive block offset
    if (tid == 63) ro[n] = v;              // grand total = E
}

// phase C: add block offsets; write both ro and cur
__global__ __launch_bounds__(256) void k_scan_c(int* __restrict__ ro,
                                                int* __restrict__ cur,
                                                const int* __restrict__ bsum, int n) {
    int base = blockIdx.x * 1024 + threadIdx.x * 4;
    int off = bsum[blockIdx.x];
    #pragma unroll
    for (int k = 0; k < 4; ++k) {
        int i = base + k;
        if (i < n) {
            int v = ro[i] + off;
            ro[i] = v;
            cur[i] = v;
        }
    }
}

__global__ void k_scatter(const int* __restrict__ src, const int* __restrict__ dst,
                          int* __restrict__ cur, int* __restrict__ ssrc, int e) {
    int i = blockIdx.x * blockDim.x + threadIdx.x;
    if (i < e) {
        int pos = atomicAdd(&cur[dst[i]], 1);
        ssrc[pos] = src[i];
    }
}

// 8 nodes per 256-thread block; 32 lanes x float4 cover one 512B row
__global__ __launch_bounds__(256) void k_agg(const float* __restrict__ h,
                                             const int* __restrict__ ro,
                                             const int* __restrict__ ssrc,
                                             float* __restrict__ agg, int n) {
    int node = blockIdx.x * 8 + (threadIdx.x >> 5);
    if (node >= n) return;
    int c4 = (threadIdx.x & 31) << 2;
    int s = ro[node], e = ro[node + 1];
    float4 acc = make_float4(0.f, 0.f, 0.f, 0.f);
    int j = s;
    for (; j + 1 < e; j += 2) {
        const float4 v0 = *(const float4*)&h[(size_t)ssrc[j] * D + c4];
        const float4 v1 = *(const float4*)&h[(size_t)ssrc[j + 1] * D + c4];
        acc.x += v0.x + v1.x;
        acc.y += v0.y + v1.y;
        acc.z += v0.z + v1.z;
        acc.w += v0.w + v1.w;
    }
    if (j < e) {
        const float4 v = *(const float4*)&h[(size_t)ssrc[j] * D + c4];
        acc.x += v.x; acc.y += v.y; acc.z += v.z; acc.w += v.w;
    }
    *(float4*)&agg[(size_t)node * D + c4] = acc;
}

// h_out = relu(agg @ Wn + h_in @ Wr + b) + x0 ; tile 64 rows x 128 cols, 256 thr
__global__ __launch_bounds__(256) void k_layer(const float* __restrict__ hin,
                                               const float* __restrict__ agg,
                                               const float* __restrict__ Wn,
                                               const float* __restrict__ Wr,
                                               const float* __restrict__ bias,
                                               const float* __restrict__ x0,
                                               float* __restrict__ hout, int n) {
    __shared__ float sa[64][D];
    __shared__ float sh[64][D];
    int tid = threadIdx.x;
    int row0 = blockIdx.x * 64;

    for (int i = tid; i < 64 * (D / 4); i += 256) {
        int r = i >> 5;
        int c4 = (i & 31) << 2;
        int gr = row0 + r;
        float4 va, vh;
        if (gr < n) {
            va = *(const float4*)&agg[(size_t)gr * D + c4];
            vh = *(const float4*)&hin[(size_t)gr * D + c4];
        } else {
            va = make_float4(0.f, 0.f, 0.f, 0.f);
            vh = va;
        }
        *(float4*)&sa[r][c4] = va;
        *(float4*)&sh[r][c4] = vh;
    }
    __syncthreads();

    int cx = (tid & 31) << 2;
    int ry = (tid >> 5) << 3;
    float acc[8][4] = {};

    #pragma unroll 4
    for (int k = 0; k < D; ++k) {
        float4 wn = *(const float4*)&Wn[k * D + cx];
        float4 wr = *(const float4*)&Wr[k * D + cx];
        #pragma unroll
        for (int r = 0; r < 8; ++r) {
            float a = sa[ry + r][k];
            float hv = sh[ry + r][k];
            acc[r][0] = fmaf(a, wn.x, fmaf(hv, wr.x, acc[r][0]));
            acc[r][1] = fmaf(a, wn.y, fmaf(hv, wr.y, acc[r][1]));
            acc[r][2] = fmaf(a, wn.z, fmaf(hv, wr.z, acc[r][2]));
            acc[r][3] = fmaf(a, wn.w, fmaf(hv, wr.w, acc[r][3]));
        }
    }

    float4 bb = *(const float4*)&bias[cx];
    #pragma unroll
    for (int r = 0; r < 8; ++r) {
        int gr = row0 + ry + r;
        if (gr >= n) break;
        float4 xr = *(const float4*)&x0[(size_t)gr * D + cx];
        float4 o;
        o.x = fmaxf(acc[r][0] + bb.x, 0.f) + xr.x;
        o.y = fmaxf(acc[r][1] + bb.y, 0.f) + xr.y;
        o.z = fmaxf(acc[r][2] + bb.z, 0.f) + xr.z;
        o.w = fmaxf(acc[r][3] + bb.w, 0.f) + xr.w;
        *(float4*)&hout[(size_t)gr * D + cx] = o;
    }
}

// out[i] = dot(h[i], fcW) + fcb ; one wave per row, 4 rows per block
__global__ __launch_bounds__(256) void k_fc(const float* __restrict__ h,
                                            const float* __restrict__ fcW,
                                            const float* __restrict__ fcb,
                                            float* __restrict__ out, int n) {
    int lane = threadIdx.x & 63;
    int row = blockIdx.x * 4 + (threadIdx.x >> 6);
    if (row >= n) return;
    const float* hr = h + (size_t)row * D;
    float p = hr[lane] * fcW[lane] + hr[64 + lane] * fcW[64 + lane];
    #pragma unroll
    for (int off = 32; off > 0; off >>= 1) p += __shfl_down(p, off, 64);
    if (lane == 0) out[row] = p + fcb[0];
}

extern "C" void kernel_launch(void* const* d_in, const int* in_sizes, int n_in,
                              void* d_out, int out_size, void* d_ws, size_t ws_size,
                              hipStream_t stream) {
    const float* x    = (const float*)d_in[0];
    const int*   ei   = (const int*)d_in[1];
    const float* Wn   = (const float*)d_in[2];
    const float* Wr   = (const float*)d_in[3];
    const float* bias = (const float*)d_in[4];
    const float* fcW  = (const float*)d_in[5];
    const float* fcb  = (const float*)d_in[6];
    float* out = (float*)d_out;

    const int n = in_sizes[0] / D;     // 50000
    const int e = in_sizes[1] / 2;     // 600000
    const int Lnum = 4;

    const int* src = ei;
    const int* dst = ei + e;

    // workspace layout
    char* ws = (char*)d_ws;
    float* h_a   = (float*)ws;                         ws += (size_t)n * D * 4;
    float* h_b   = (float*)ws;                         ws += (size_t)n * D * 4;
    float* agg   = (float*)ws;                         ws += (size_t)n * D * 4;
    int*   ro    = (int*)ws;                           ws += (size_t)(n + 1) * 4;
    int*   cur   = (int*)ws;                           ws += (size_t)n * 4;
    int*   ssrc  = (int*)ws;                           ws += (size_t)e * 4;
    int*   bsum  = (int*)ws;                           ws += 256 * 4;
    (void)ws_size;

    const int nscan = (n + 1023) / 1024;   // 49 blocks

    // ---- CSR build
    k_zero_i32<<<(n + 255) / 256, 256, 0, stream>>>(cur, n);
    k_hist<<<(e + 255) / 256, 256, 0, stream>>>(dst, cur, e);
    k_scan_a<<<nscan, 256, 0, stream>>>(cur, ro, bsum, n);
    k_scan_b<<<1, 64, 0, stream>>>(bsum, ro, nscan, n);
    k_scan_c<<<nscan, 256, 0, stream>>>(ro, cur, bsum, n);
    k_scatter<<<(e + 255) / 256, 256, 0, stream>>>(src, dst, cur, ssrc, e);

    // ---- layers
    const float* hin = x;
    float* hout = h_a;
    int gemm_blocks = (n + 63) / 64;
    int agg_blocks = (n + 7) / 8;
    for (int l = 0; l < Lnum; ++l) {
        k_agg<<<agg_blocks, 256, 0, stream>>>(hin, ro, ssrc, agg, n);
        k_layer<<<gemm_blocks, 256, 0, stream>>>(hin, agg,
                Wn + (size_t)l * D * D, Wr + (size_t)l * D * D,
                bias + (size_t)l * D, x, hout, n);
        hin = hout;
        hout = (hout == h_a) ? h_b : h_a;
    }

    // ---- final fc
    k_fc<<<(n + 3) / 4, 256, 0, stream>>>(hin, fcW, fcb, out, n);
}